// Round 6
// baseline (204.941 us; speedup 1.0000x reference)
//
#include <hip/hip_runtime.h>
#include <hip/hip_bf16.h>

#define T_  30
#define B_  64
#define V_  32
#define F_  128
#define L_  64
#define LF_ 64
#define TH_ 20
#define H_  4
#define HD_ 32

typedef __attribute__((ext_vector_type(8))) short bf16x8;   // 8 bf16 = 4 VGPR
typedef __attribute__((ext_vector_type(4))) short bf16x4;   // 4 bf16 = 2 VGPR
typedef __attribute__((ext_vector_type(4))) float f32x4;
#define MFMA(a,b,c) __builtin_amdgcn_mfma_f32_16x16x32_bf16(a, b, c, 0, 0, 0)

// K=16 bf16 MFMA (v_mfma_f32_16x16x16_bf16), CDNA2 "1k" builtin spelling.
// __HIP_DEVICE_COMPILE__ guard keeps the x86 host pass from parsing it.
__device__ __forceinline__ f32x4 mfma16(bf16x4 a, bf16x4 b, f32x4 c) {
#if defined(__HIP_DEVICE_COMPILE__)
    return __builtin_amdgcn_mfma_f32_16x16x16bf16_1k(a, b, c, 0, 0, 0);
#else
    (void)a; (void)b; return c;
#endif
}

__device__ __forceinline__ float bf1(unsigned short u) {
    unsigned int x = ((unsigned int)u) << 16; float f; __builtin_memcpy(&f, &x, 4); return f;
}
// pack two f32 -> two bf16 (RTNE, v_cvt_pk_bf16_f32); lo half = a, hi half = b
__device__ __forceinline__ unsigned int cvtpk(float a, float b) {
    __hip_bfloat162 h = __float22bfloat162_rn(make_float2(a, b));
    unsigned int r; __builtin_memcpy(&r, &h, 4); return r;
}
__device__ __forceinline__ void st4pk(unsigned short* p, float a, float b, float c, float d) {
    uint2 u = { cvtpk(a, b), cvtpk(c, d) };
    *(uint2*)p = u;
}
// XOR-16B swizzle keyed on row&7 (T2): ushort-index helpers.
__device__ __forceinline__ int swz128(int r, int c) { return r * 128 + (c ^ ((r & 7) << 3)); }
__device__ __forceinline__ int swz64 (int r, int c) { return r * 64  + (c ^ ((r & 7) << 3)); }
// Load one MFMA A/B-fragment (8 bf16) from a weight matrix of either dtype.
__device__ __forceinline__ bf16x8 ldWfrag(const void* W, int off, bool isBf16) {
    if (isBf16) return *(const bf16x8*)((const unsigned short*)W + off);
    const float* p = (const float*)W + off;
    float4 a = *(const float4*)p;
    float4 b = *(const float4*)(p + 4);
    uint4 u = { cvtpk(a.x, a.y), cvtpk(a.z, a.w), cvtpk(b.x, b.y), cvtpk(b.z, b.w) };
    bf16x8 r; __builtin_memcpy(&r, &u, 16); return r;
}

// One block per TWO (b,v) problems, processed back-to-back with a register
// prefetch pipeline: bv1's global loads are issued right after bv0's barrier 1
// and land during bv0's entire compute chain (T14 issue-early / write-late).
// Grid 1024 = exactly 4 blocks/CU resident (LDS 40960 B), one generation.
// Per-bv structure is the round-5 validated kernel: 8 waves, wave w ->
// (head h=w>>1, half s=w&1); JIT weights; V exchanged via sVx; softmax
// normalization deferred to PV epilogue; fragment-identity K=16 PV.
__global__ __launch_bounds__(512, 8)
void lane_attn_kernel(const void* __restrict__ veh,    // [T,B,V,F]
                      const void* __restrict__ lanes,  // [B,V,L,LF]
                      const void* __restrict__ maskp,  // [TH,B,V,L] uint8 or int32 (probed)
                      const void* __restrict__ Wk, const void* __restrict__ Wv,
                      const void* __restrict__ Wq, const void* __restrict__ Wc,
                      float* __restrict__ outp)        // [T,B,V,F] fp32
{
    const int bv0   = blockIdx.x * 2;
    const int tid   = threadIdx.x;
    const int w     = tid >> 6;
    const int h     = w >> 1;      // head
    const int shalf = w & 1;       // half within head
    const int lane  = tid & 63;
    const int quad  = lane >> 4;
    const int lm    = lane & 15;
    const int fbase = h * 32;
    const int fs    = fbase + shalf * 16;         // wave's own 16-col f-slice
    const int pfs   = fbase + (1 - shalf) * 16;   // partner's f-slice

    // LDS (ushort units), 20480 ushorts = 40960 B total:
    //   sK    [64 l][128 f]   8192 u  (written B-K, read scores)
    //   sReg1 8192 u: sLanes [64][64] + sVehB [32][128]  (A..C)
    //                 -> after bar2: sVx [8 slots][1024]  (V-fragment exchange)
    //   sReg2 4096 u: sQ [32][128] (C..scores) -> after bar2.5: sO [32][128]
    __shared__ __align__(16) unsigned short sK   [8192];
    __shared__ __align__(16) unsigned short sReg1[8192];
    __shared__ __align__(16) unsigned short sReg2[4096];
    unsigned short* sLanes = sReg1;
    unsigned short* sVehB  = sReg1 + 4096;
    unsigned short* sVx    = sReg1;
    unsigned short* sQ     = sReg2;
    unsigned short* sO     = sReg2;

    // ---------- per-wave probes (wave-uniform, no LDS/barrier) ----------
    const unsigned short* vh16 = (const unsigned short*)veh;
    const int field = (vh16[2 * lane] >> 7) & 0xFF;
    const bool isBf16 = __popcll(__ballot(field >= 100 && field <= 130)) >= 32;
    const unsigned char* mbp = (const unsigned char*)maskp;
    const bool maskByte = (__ballot(mbp[4 * lane + 1] != 0) != 0ULL);

    // ---------- prefetch registers (staging for one bv, register-staged) ----------
    float4 lpf0, lpf1, vpf0, vpf1;   // fp32 path: lanes x8, veh x8
    uint4  lpb,  vpb;                // bf16 path: lanes x8, veh x8
    auto issuePF = [&](int bvn) {
        if (isBf16) {
            lpb = *(const uint4*)((const unsigned short*)lanes + (size_t)bvn * 4096 + tid * 8);
            const int t = tid >> 4, g = tid & 15;
            uint4 z = {0, 0, 0, 0}; vpb = z;
            if (t < T_)
                vpb = *(const uint4*)((const unsigned short*)veh + ((size_t)t * (B_ * V_) + bv0) * F_
                                      + (size_t)(bvn - bv0) * F_ + g * 8);
        } else {
            const float4* lf4 = (const float4*)lanes;
            lpf0 = lf4[bvn * 1024 + tid];
            lpf1 = lf4[bvn * 1024 + tid + 512];
            vpf0 = make_float4(0.f, 0.f, 0.f, 0.f);
            vpf1 = vpf0;
            {   const int u = tid;        const int t = u >> 5;
                if (t < T_) vpf0 = ((const float4*)veh)[((size_t)t * (B_ * V_) + bvn) * 32 + (u & 31)]; }
            {   const int u = tid + 512;  const int t = u >> 5;
                if (t < T_) vpf1 = ((const float4*)veh)[((size_t)t * (B_ * V_) + bvn) * 32 + (u & 31)]; }
        }
    };
    auto stageWrite = [&]() {
        if (isBf16) {
            *(uint4*)&sLanes[swz64(tid >> 3, (tid & 7) * 8)] = lpb;
            *(uint4*)&sVehB[swz128(tid >> 4, (tid & 15) * 8)] = vpb;
        } else {
            {   const int u = tid;       const int l = u >> 4, c = (u & 15) * 4;
                uint2 y = { cvtpk(lpf0.x, lpf0.y), cvtpk(lpf0.z, lpf0.w) };
                *(uint2*)&sLanes[swz64(l, c)] = y; }
            {   const int u = tid + 512; const int l = u >> 4, c = (u & 15) * 4;
                uint2 y = { cvtpk(lpf1.x, lpf1.y), cvtpk(lpf1.z, lpf1.w) };
                *(uint2*)&sLanes[swz64(l, c)] = y; }
            {   const int u = tid;       const int t = u >> 5, c = (u & 31) * 4;
                uint2 y = { cvtpk(vpf0.x, vpf0.y), cvtpk(vpf0.z, vpf0.w) };
                *(uint2*)&sVehB[swz128(t, c)] = y; }
            {   const int u = tid + 512; const int t = u >> 5, c = (u & 31) * 4;
                uint2 y = { cvtpk(vpf1.x, vpf1.y), cvtpk(vpf1.z, vpf1.w) };
                *(uint2*)&sVehB[swz128(t, c)] = y; }
        }
    };

    issuePF(bv0);   // bv0 staging loads in flight from kernel entry

    #pragma unroll
    for (int it = 0; it < 2; ++it) {
        const int bv = bv0 + it;

        // ---------- per-lane mask OR over TH (l = lane) -> wave-uniform bitmask ----------
        bool ok;
        {
            const int* mi = (const int*)maskp;
            int o = 0;
            #pragma unroll
            for (int th = 0; th < TH_; ++th) {
                const size_t e = (size_t)th * (B_ * V_ * L_) + (size_t)bv * L_ + lane;
                o |= maskByte ? (int)mbp[e] : mi[e];
            }
            ok = (o != 0);
        }
        const unsigned long long mok = __ballot(ok);   // bit l = mask for lane-row l

        // ---------- staging write from prefetch regs (waits on the loads) ----------
        stageWrite();
        __syncthreads();   // barrier 1: staging visible

        // issue next bv's staging loads NOW — they land during this bv's compute
        if (it == 0) issuePF(bv0 + 1);

        // ---------- Phase B-K: K projection (swapped: A=Wk, JIT) -> sK[l][f] packed ----------
        {
            bf16x8 wbK[2];
            #pragma unroll
            for (int kt = 0; kt < 2; ++kt)
                wbK[kt] = ldWfrag(Wk, (fs + lm) * 64 + kt * 32 + quad * 8, isBf16);
            f32x4 accK[4];
            #pragma unroll
            for (int mt = 0; mt < 4; ++mt) accK[mt] = (f32x4)0.f;
            #pragma unroll
            for (int kt = 0; kt < 2; ++kt) {
                bf16x8 a[4];
                #pragma unroll
                for (int mt = 0; mt < 4; ++mt)
                    a[mt] = *(const bf16x8*)&sLanes[swz64(mt * 16 + lm, kt * 32 + quad * 8)];
                #pragma unroll
                for (int mt = 0; mt < 4; ++mt) accK[mt] = MFMA(wbK[kt], a[mt], accK[mt]);  // C[f][l]
            }
            #pragma unroll
            for (int mt = 0; mt < 4; ++mt)
                st4pk(&sK[swz128(mt * 16 + lm, fs + quad * 4)],
                      accK[mt][0], accK[mt][1], accK[mt][2], accK[mt][3]);
        }

        // ---------- Phase B-V: V projection (unswapped, JIT) -> registers as PV A-frags ----------
        bf16x4 vb[4];   // vb[kt]: V[l=kt*16+quad*4+r][f=fs+lm]
        {
            bf16x8 wbV[2];
            #pragma unroll
            for (int kt = 0; kt < 2; ++kt)
                wbV[kt] = ldWfrag(Wv, (fs + lm) * 64 + kt * 32 + quad * 8, isBf16);
            f32x4 accV[4];
            #pragma unroll
            for (int mt = 0; mt < 4; ++mt) accV[mt] = (f32x4)0.f;
            #pragma unroll
            for (int kt = 0; kt < 2; ++kt) {
                bf16x8 a[4];
                #pragma unroll
                for (int mt = 0; mt < 4; ++mt)
                    a[mt] = *(const bf16x8*)&sLanes[swz64(mt * 16 + lm, kt * 32 + quad * 8)];
                #pragma unroll
                for (int mt = 0; mt < 4; ++mt) accV[mt] = MFMA(a[mt], wbV[kt], accV[mt]);  // C[l][f]
            }
            #pragma unroll
            for (int mt = 0; mt < 4; ++mt) {
                uint2 y = { cvtpk(accV[mt][0], accV[mt][1]), cvtpk(accV[mt][2], accV[mt][3]) };
                __builtin_memcpy(&vb[mt], &y, 8);
            }
        }

        // ---------- Phase C: Q projection (swapped: A=Wq, JIT) -> sQ[t][g] packed, pre-scaled ----------
        {
            bf16x8 wq[4];
            #pragma unroll
            for (int kt = 0; kt < 4; ++kt)
                wq[kt] = ldWfrag(Wq, (fs + lm) * 128 + kt * 32 + quad * 8, isBf16);
            f32x4 acc[2];
            acc[0] = (f32x4)0.f; acc[1] = (f32x4)0.f;
            #pragma unroll
            for (int kt = 0; kt < 4; ++kt) {
                bf16x8 b[2];
                #pragma unroll
                for (int nt = 0; nt < 2; ++nt)
                    b[nt] = *(const bf16x8*)&sVehB[swz128(nt * 16 + lm, kt * 32 + quad * 8)];
                #pragma unroll
                for (int nt = 0; nt < 2; ++nt) acc[nt] = MFMA(wq[kt], b[nt], acc[nt]);     // C[g][t]
            }
            const float sc = 0.17677669529663687f;   // 1/sqrt(32)
            #pragma unroll
            for (int nt = 0; nt < 2; ++nt)
                st4pk(&sQ[swz128(nt * 16 + lm, fs + quad * 4)],
                      acc[nt][0] * sc, acc[nt][1] * sc, acc[nt][2] * sc, acc[nt][3] * sc);
        }
        __syncthreads();   // barrier 2: sK/sQ visible; staging dead -> sVx writable

        // ---------- V-fragment exchange: wave slot w ----------
        #pragma unroll
        for (int kt = 0; kt < 4; ++kt) {
            uint2 y; __builtin_memcpy(&y, &vb[kt], 8);
            *(uint2*)&sVx[w * 1024 + kt * 256 + lane * 4] = y;
        }

        // ---------- Scores + exp/mask; UNNORMALIZED P -> registers only; inv kept ----------
        bf16x4 pa[4];   // pa[kt]: exp(S)[l=kt*16+quad*4+r][t=shalf*16+lm]
        float inv;
        {
            bf16x8 a[4], b;
            #pragma unroll
            for (int mt = 0; mt < 4; ++mt)
                a[mt] = *(const bf16x8*)&sK[swz128(mt * 16 + lm, fbase + quad * 8)];
            b = *(const bf16x8*)&sQ[swz128(shalf * 16 + lm, fbase + quad * 8)];
            const int t = shalf * 16 + lm;
            const bool tok = (t < T_);
            const unsigned long long msh = (tok ? mok : 0ULL) >> (quad * 4);
            const unsigned int mlo = (unsigned int)msh, mhi = (unsigned int)(msh >> 32);
            float psum = 0.f;
            #pragma unroll
            for (int mt = 0; mt < 4; ++mt) {
                f32x4 acc = MFMA(a[mt], b, (f32x4)0.f);   // C[l][t], col t = lm
                const unsigned int mw = (mt >= 2) ? mhi : mlo;
                const int bp = (mt * 16) & 31;
                float e0 = ((mw >> (bp + 0)) & 1u) ? __expf(acc[0]) : 0.f;
                float e1 = ((mw >> (bp + 1)) & 1u) ? __expf(acc[1]) : 0.f;
                float e2 = ((mw >> (bp + 2)) & 1u) ? __expf(acc[2]) : 0.f;
                float e3 = ((mw >> (bp + 3)) & 1u) ? __expf(acc[3]) : 0.f;
                psum += (e0 + e1) + (e2 + e3);
                uint2 y = { cvtpk(e0, e1), cvtpk(e2, e3) };
                __builtin_memcpy(&pa[mt], &y, 8);
            }
            // full row-sum over l: 4 quads hold disjoint l for the same t
            psum += __shfl_xor(psum, 16, 64);
            psum += __shfl_xor(psum, 32, 64);
            inv = (psum > 0.f) ? 1.f / psum : 0.f;   // pad/masked rows -> exact 0
        }
        __syncthreads();   // barrier 2.5: sVx visible; sK/sQ dead -> sO writable

        // ---------- PV: O[f own+partner][t own] via mfma16; normalize by lane-local inv ----------
        {
            f32x4 o0 = (f32x4)0.f, o1 = (f32x4)0.f;   // own-f tile, partner-f tile
            #pragma unroll
            for (int kt = 0; kt < 4; ++kt) {
                uint2 y = *(const uint2*)&sVx[(w ^ 1) * 1024 + kt * 256 + lane * 4];
                bf16x4 vx; __builtin_memcpy(&vx, &y, 8);
                o0 = mfma16(vb[kt], pa[kt], o0);
                o1 = mfma16(vx,     pa[kt], o1);
            }
            // C[f][t]: col t = shalf*16+lm (lane-local inv), rows f = f0+quad*4+r
            const int t = shalf * 16 + lm;
            st4pk(&sO[swz128(t, fs  + quad * 4)],
                  o0[0] * inv, o0[1] * inv, o0[2] * inv, o0[3] * inv);
            st4pk(&sO[swz128(t, pfs + quad * 4)],
                  o1[0] * inv, o1[1] * inv, o1[2] * inv, o1[3] * inv);
        }

        // ---------- residual preload (fp32-exact; issued before barrier 3) ----------
        float4 res[2];
        #pragma unroll
        for (int nt = 0; nt < 2; ++nt) {
            const int t = nt * 16 + lm;
            res[nt] = make_float4(0.f, 0.f, 0.f, 0.f);
            if (t < T_) {
                const size_t off = ((size_t)t * (B_ * V_) + bv) * F_ + fs + quad * 4;
                if (isBf16) {
                    ushort4 u = *(const ushort4*)((const unsigned short*)veh + off);
                    res[nt] = make_float4(bf1(u.x), bf1(u.y), bf1(u.z), bf1(u.w));
                } else {
                    res[nt] = *(const float4*)((const float*)veh + off);
                }
            }
        }
        __syncthreads();   // barrier 3: sO complete across waves

        // ---------- Phase E (swapped: A=Wc, JIT): out = O @ Wc^T + veh ----------
        {
            bf16x8 wc[4];
            #pragma unroll
            for (int kt = 0; kt < 4; ++kt)
                wc[kt] = ldWfrag(Wc, (fs + lm) * 128 + kt * 32 + quad * 8, isBf16);
            f32x4 acc[2];
            acc[0] = (f32x4)0.f; acc[1] = (f32x4)0.f;
            #pragma unroll
            for (int kt = 0; kt < 4; ++kt) {
                bf16x8 b[2];
                #pragma unroll
                for (int nt = 0; nt < 2; ++nt)
                    b[nt] = *(const bf16x8*)&sO[swz128(nt * 16 + lm, kt * 32 + quad * 8)];
                #pragma unroll
                for (int nt = 0; nt < 2; ++nt) acc[nt] = MFMA(wc[kt], b[nt], acc[nt]);    // C[g][t]
            }
            #pragma unroll
            for (int nt = 0; nt < 2; ++nt) {
                const int t = nt * 16 + lm;
                if (t < T_) {
                    const size_t off = ((size_t)t * (B_ * V_) + bv) * F_ + fs + quad * 4;
                    float4 o = make_float4(acc[nt][0] + res[nt].x, acc[nt][1] + res[nt].y,
                                           acc[nt][2] + res[nt].z, acc[nt][3] + res[nt].w);
                    *(float4*)&outp[off] = o;
                }
            }
        }
        // No extra barrier needed before next iteration's staging writes:
        // staging targets sReg1, which no wave touches after barrier 2.5's PV
        // reads; phase E only reads sReg2 (sO) and global memory.
    }
}

extern "C" void kernel_launch(void* const* d_in, const int* in_sizes, int n_in,
                              void* d_out, int out_size, void* d_ws, size_t ws_size,
                              hipStream_t stream) {
    (void)in_sizes; (void)n_in; (void)out_size; (void)d_ws; (void)ws_size;
    lane_attn_kernel<<<dim3(B_ * V_ / 2), dim3(512), 0, stream>>>(
        d_in[0], d_in[1], d_in[2], d_in[3], d_in[4], d_in[5], d_in[6],
        (float*)d_out);
}

// Round 7
// 167.212 us; speedup vs baseline: 1.2256x; 1.2256x over previous
//
#include <hip/hip_runtime.h>
#include <hip/hip_bf16.h>

#define T_  30
#define B_  64
#define V_  32
#define F_  128
#define L_  64
#define LF_ 64
#define TH_ 20
#define H_  4
#define HD_ 32
#define G_  4      // (b,v) problems per block

typedef __attribute__((ext_vector_type(8))) short bf16x8;   // 8 bf16 = 4 VGPR
typedef __attribute__((ext_vector_type(4))) short bf16x4;   // 4 bf16 = 2 VGPR
typedef __attribute__((ext_vector_type(4))) float f32x4;
#define MFMA(a,b,c) __builtin_amdgcn_mfma_f32_16x16x32_bf16(a, b, c, 0, 0, 0)

// K=16 bf16 MFMA (v_mfma_f32_16x16x16_bf16), CDNA2 "1k" builtin spelling.
// __HIP_DEVICE_COMPILE__ guard keeps the x86 host pass from parsing it.
__device__ __forceinline__ f32x4 mfma16(bf16x4 a, bf16x4 b, f32x4 c) {
#if defined(__HIP_DEVICE_COMPILE__)
    return __builtin_amdgcn_mfma_f32_16x16x16bf16_1k(a, b, c, 0, 0, 0);
#else
    (void)a; (void)b; return c;
#endif
}

// async global->LDS, 16B per lane; LDS dest = wave-uniform base + lane*16.
__device__ __forceinline__ void gld16(const void* g, unsigned short* l) {
#if defined(__HIP_DEVICE_COMPILE__)
    __builtin_amdgcn_global_load_lds(
        (const __attribute__((address_space(1))) unsigned int*)g,
        (__attribute__((address_space(3))) unsigned int*)l, 16, 0, 0);
#else
    (void)g; (void)l;
#endif
}

// raw barriers (T4): BAR_VM drains everything (stage buffer ready);
// BAR_LDS orders LDS only -- in-flight global_load_lds stays in flight.
#define BAR_VM()  asm volatile("s_waitcnt vmcnt(0) lgkmcnt(0)\n\ts_barrier" ::: "memory")
#define BAR_LDS() asm volatile("s_waitcnt lgkmcnt(0)\n\ts_barrier" ::: "memory")

__device__ __forceinline__ float bf1(unsigned short u) {
    unsigned int x = ((unsigned int)u) << 16; float f; __builtin_memcpy(&f, &x, 4); return f;
}
__device__ __forceinline__ unsigned int cvtpk(float a, float b) {
    __hip_bfloat162 h = __float22bfloat162_rn(make_float2(a, b));
    unsigned int r; __builtin_memcpy(&r, &h, 4); return r;
}
__device__ __forceinline__ void st4pk(unsigned short* p, float a, float b, float c, float d) {
    uint2 u = { cvtpk(a, b), cvtpk(c, d) };
    *(uint2*)p = u;
}
// XOR-16B swizzle keyed on row&7 (T2), ushort-index helpers (granule involution).
__device__ __forceinline__ int swz128(int r, int c) { return r * 128 + (c ^ ((r & 7) << 3)); }
__device__ __forceinline__ int swz64 (int r, int c) { return r * 64  + (c ^ ((r & 7) << 3)); }
__device__ __forceinline__ bf16x8 ldWfrag(const void* W, int off, bool isBf16) {
    if (isBf16) return *(const bf16x8*)((const unsigned short*)W + off);
    const float* p = (const float*)W + off;
    float4 a = *(const float4*)p;
    float4 b = *(const float4*)(p + 4);
    uint4 u = { cvtpk(a.x, a.y), cvtpk(a.z, a.w), cvtpk(b.x, b.y), cvtpk(b.z, b.w) };
    bf16x8 r; __builtin_memcpy(&r, &u, 16); return r;
}

// One block per FOUR (b,v): double-buffered LDS staging via global_load_lds,
// issued at the top of compute(i) for bv(i+1) and left in flight across the
// LDS-only barriers (counted-vmcnt discipline). Grid 512 = 2 blocks/CU, one
// generation, continuous HBM streaming. Per-bv structure = round-5 validated:
// 8 waves, wave w -> (head h=w>>1, half s=w&1); fragment-identity K=16 PV;
// deferred softmax normalization. V computed for BOTH halves (wbVp preloaded,
// +8 cheap MFMA) -> no sVx exchange, 3 barriers/bv. Residual from LDS staging
// (bf16 path, bit-exact). LDS 64KB; launch_bounds(512,4) -> 128-VGPR cap.
__global__ __launch_bounds__(512, 4)
void lane_attn_kernel(const void* __restrict__ veh,    // [T,B,V,F]
                      const void* __restrict__ lanes,  // [B,V,L,LF]
                      const void* __restrict__ maskp,  // [TH,B,V,L] uint8 or int32 (probed)
                      const void* __restrict__ Wk, const void* __restrict__ Wv,
                      const void* __restrict__ Wq, const void* __restrict__ Wc,
                      float* __restrict__ outp)        // [T,B,V,F] fp32
{
    const int bv0   = blockIdx.x * G_;
    const int tid   = threadIdx.x;
    const int w     = tid >> 6;
    const int h     = w >> 1;      // head
    const int shalf = w & 1;       // half within head
    const int lane  = tid & 63;
    const int quad  = lane >> 4;
    const int lm    = lane & 15;
    const int fbase = h * 32;
    const int fs    = fbase + shalf * 16;         // wave's own 16-col f-slice
    const int pfs   = fbase + (1 - shalf) * 16;   // partner's f-slice

    // LDS (ushort units), 32768 u = 65536 B:
    //   sK  [64 l][128 f]  8192 u   sQ [32][128] 4096 u   sO [32][128] 4096 u
    //   sStg[2][8192]: per buf, sLanes [64][64] @0 + sVehB [32][128] @4096
    __shared__ __align__(16) unsigned short sK  [8192];
    __shared__ __align__(16) unsigned short sQ  [4096];
    __shared__ __align__(16) unsigned short sO  [4096];
    __shared__ __align__(16) unsigned short sStg[16384];

    // ---------- per-wave probes (wave-uniform) ----------
    const unsigned short* vh16 = (const unsigned short*)veh;
    const int field = (vh16[2 * lane] >> 7) & 0xFF;
    const bool isBf16 = __popcll(__ballot(field >= 100 && field <= 130)) >= 32;
    const unsigned char* mbp = (const unsigned char*)maskp;
    const bool maskByte = (__ballot(mbp[4 * lane + 1] != 0) != 0ULL);

    // zero the t=30,31 pad rows of both veh staging buffers (never re-written:
    // the guarded global_load_lds lanes skip them every iteration)
    if (tid >= 480) {
        uint4 z = {0, 0, 0, 0};
        *(uint4*)&sStg[tid * 8 + 4096] = z;
        *(uint4*)&sStg[8192 + tid * 8 + 4096] = z;
    }

    // ---------- mask bitmasks for all G_ bvs (wave-uniform u64, static idx) ----------
    unsigned long long mokA[G_];
    #pragma unroll
    for (int g = 0; g < G_; ++g) {
        const int* mi = (const int*)maskp;
        int o = 0;
        #pragma unroll
        for (int th = 0; th < TH_; ++th) {
            const size_t e = (size_t)th * (B_ * V_ * L_) + (size_t)(bv0 + g) * L_ + lane;
            o |= maskByte ? (int)mbp[e] : mi[e];
        }
        mokA[g] = __ballot(o != 0);
    }

    // ---------- persistent weight fragments (24 VGPR): K own, V own+partner ----------
    bf16x8 wbK[2], wbVo[2], wbVp[2];
    #pragma unroll
    for (int kt = 0; kt < 2; ++kt) {
        wbK[kt]  = ldWfrag(Wk, (fs  + lm) * 64 + kt * 32 + quad * 8, isBf16);
        wbVo[kt] = ldWfrag(Wv, (fs  + lm) * 64 + kt * 32 + quad * 8, isBf16);
        wbVp[kt] = ldWfrag(Wv, (pfs + lm) * 64 + kt * 32 + quad * 8, isBf16);
    }

    // ---------- staging (bf16: async, pre-swizzled source / linear dest) ----------
    const int sl_l = tid >> 3, sl_g = (tid & 7)  ^ (sl_l & 7);
    const int sv_t = tid >> 4, sv_g = (tid & 15) ^ (sv_t & 7);
    const unsigned short* lanesU = (const unsigned short*)lanes;
    const unsigned short* vehU   = (const unsigned short*)veh;
    auto stageIssue = [&](int buf, int bvn) {
        gld16(lanesU + (size_t)bvn * 4096 + sl_l * 64 + sl_g * 8,
              &sStg[buf * 8192 + w * 512]);
        if (sv_t < T_)
            gld16(vehU + ((size_t)sv_t * (B_ * V_) + bvn) * 128 + sv_g * 8,
                  &sStg[buf * 8192 + 4096 + w * 512]);
    };
    auto stageF32 = [&](int buf, int bvn) {   // fp32 fallback: serial reg-stage
        const float4* lf4 = (const float4*)lanes;
        #pragma unroll
        for (int rr = 0; rr < 2; ++rr) {
            const int u = tid + rr * 512;
            const int l = u >> 4, c = (u & 15) * 4;
            float4 x = lf4[bvn * 1024 + u];
            uint2 y = { cvtpk(x.x, x.y), cvtpk(x.z, x.w) };
            *(uint2*)&sStg[buf * 8192 + swz64(l, c)] = y;
        }
        #pragma unroll
        for (int rr = 0; rr < 2; ++rr) {
            const int u = tid + rr * 512;
            const int t = u >> 5, c = (u & 31) * 4;
            uint2 y = {0, 0};
            if (t < T_) {
                float4 x = ((const float4*)veh)[((size_t)t * (B_ * V_) + bvn) * 32 + (u & 31)];
                y.x = cvtpk(x.x, x.y); y.y = cvtpk(x.z, x.w);
            }
            *(uint2*)&sStg[buf * 8192 + 4096 + swz128(t, c)] = y;
        }
    };

    if (isBf16) stageIssue(0, bv0);   // prologue: bv0 loads in flight

    #pragma unroll
    for (int it = 0; it < G_; ++it) {
        const int cur = it & 1;
        const int bv  = bv0 + it;
        const unsigned long long mok = mokA[it];
        const unsigned short* sLanes = &sStg[cur * 8192];
        const unsigned short* sVehB  = &sStg[cur * 8192 + 4096];

        if (isBf16) {
            BAR_VM();                                   // stage[cur] ready, all waves
            if (it < G_ - 1) stageIssue(cur ^ 1, bv + 1);   // next bv in flight
        } else {
            stageF32(cur, bv);
            BAR_VM();
        }

        // ---------- Phase B-K: K projection (swapped: A=Wk) -> sK[l][f] packed ----------
        {
            f32x4 accK[4];
            #pragma unroll
            for (int mt = 0; mt < 4; ++mt) accK[mt] = (f32x4)0.f;
            #pragma unroll
            for (int kt = 0; kt < 2; ++kt) {
                bf16x8 a[4];
                #pragma unroll
                for (int mt = 0; mt < 4; ++mt)
                    a[mt] = *(const bf16x8*)&sLanes[swz64(mt * 16 + lm, kt * 32 + quad * 8)];
                #pragma unroll
                for (int mt = 0; mt < 4; ++mt) accK[mt] = MFMA(wbK[kt], a[mt], accK[mt]);  // C[f][l]
            }
            #pragma unroll
            for (int mt = 0; mt < 4; ++mt)
                st4pk(&sK[swz128(mt * 16 + lm, fs + quad * 4)],
                      accK[mt][0], accK[mt][1], accK[mt][2], accK[mt][3]);
        }

        // ---------- Phase B-V: V projection, BOTH f-halves -> PV A-frags in regs ----------
        bf16x4 vb[4], vx[4];   // vb: V[l=kt*16+quad*4+r][fs+lm], vx: partner slice
        {
            f32x4 aco[4], acp[4];
            #pragma unroll
            for (int mt = 0; mt < 4; ++mt) { aco[mt] = (f32x4)0.f; acp[mt] = (f32x4)0.f; }
            #pragma unroll
            for (int kt = 0; kt < 2; ++kt) {
                bf16x8 a[4];
                #pragma unroll
                for (int mt = 0; mt < 4; ++mt)
                    a[mt] = *(const bf16x8*)&sLanes[swz64(mt * 16 + lm, kt * 32 + quad * 8)];
                #pragma unroll
                for (int mt = 0; mt < 4; ++mt) {
                    aco[mt] = MFMA(a[mt], wbVo[kt], aco[mt]);   // C[l][f own]
                    acp[mt] = MFMA(a[mt], wbVp[kt], acp[mt]);   // C[l][f partner]
                }
            }
            #pragma unroll
            for (int mt = 0; mt < 4; ++mt) {
                uint2 yo = { cvtpk(aco[mt][0], aco[mt][1]), cvtpk(aco[mt][2], aco[mt][3]) };
                uint2 yp = { cvtpk(acp[mt][0], acp[mt][1]), cvtpk(acp[mt][2], acp[mt][3]) };
                __builtin_memcpy(&vb[mt], &yo, 8);
                __builtin_memcpy(&vx[mt], &yp, 8);
            }
        }

        // ---------- Phase C: Q projection (swapped: A=Wq, JIT) -> sQ, pre-scaled ----------
        {
            bf16x8 wq[4];
            #pragma unroll
            for (int kt = 0; kt < 4; ++kt)
                wq[kt] = ldWfrag(Wq, (fs + lm) * 128 + kt * 32 + quad * 8, isBf16);
            f32x4 acc[2];
            acc[0] = (f32x4)0.f; acc[1] = (f32x4)0.f;
            #pragma unroll
            for (int kt = 0; kt < 4; ++kt) {
                bf16x8 b[2];
                #pragma unroll
                for (int nt = 0; nt < 2; ++nt)
                    b[nt] = *(const bf16x8*)&sVehB[swz128(nt * 16 + lm, kt * 32 + quad * 8)];
                #pragma unroll
                for (int nt = 0; nt < 2; ++nt) acc[nt] = MFMA(wq[kt], b[nt], acc[nt]);     // C[g][t]
            }
            const float sc = 0.17677669529663687f;   // 1/sqrt(32)
            #pragma unroll
            for (int nt = 0; nt < 2; ++nt)
                st4pk(&sQ[swz128(nt * 16 + lm, fs + quad * 4)],
                      acc[nt][0] * sc, acc[nt][1] * sc, acc[nt][2] * sc, acc[nt][3] * sc);
        }
        BAR_LDS();   // sK/sQ visible; stage loads stay in flight

        // ---------- Scores + exp/mask; UNNORMALIZED P in regs; lane-local inv ----------
        bf16x4 pa[4];
        float inv;
        {
            bf16x8 a[4], b;
            #pragma unroll
            for (int mt = 0; mt < 4; ++mt)
                a[mt] = *(const bf16x8*)&sK[swz128(mt * 16 + lm, fbase + quad * 8)];
            b = *(const bf16x8*)&sQ[swz128(shalf * 16 + lm, fbase + quad * 8)];
            const int t = shalf * 16 + lm;
            const bool tok = (t < T_);
            const unsigned long long msh = (tok ? mok : 0ULL) >> (quad * 4);
            const unsigned int mlo = (unsigned int)msh, mhi = (unsigned int)(msh >> 32);
            float psum = 0.f;
            #pragma unroll
            for (int mt = 0; mt < 4; ++mt) {
                f32x4 acc = MFMA(a[mt], b, (f32x4)0.f);   // C[l][t], col t = lm
                const unsigned int mw = (mt >= 2) ? mhi : mlo;
                const int bp = (mt * 16) & 31;
                float e0 = ((mw >> (bp + 0)) & 1u) ? __expf(acc[0]) : 0.f;
                float e1 = ((mw >> (bp + 1)) & 1u) ? __expf(acc[1]) : 0.f;
                float e2 = ((mw >> (bp + 2)) & 1u) ? __expf(acc[2]) : 0.f;
                float e3 = ((mw >> (bp + 3)) & 1u) ? __expf(acc[3]) : 0.f;
                psum += (e0 + e1) + (e2 + e3);
                uint2 y = { cvtpk(e0, e1), cvtpk(e2, e3) };
                __builtin_memcpy(&pa[mt], &y, 8);
            }
            psum += __shfl_xor(psum, 16, 64);
            psum += __shfl_xor(psum, 32, 64);
            inv = (psum > 0.f) ? 1.f / psum : 0.f;   // pad/masked rows -> exact 0
        }

        // ---------- PV (all-register): O[f own+partner][t own], normalized ----------
        {
            f32x4 o0 = (f32x4)0.f, o1 = (f32x4)0.f;
            #pragma unroll
            for (int kt = 0; kt < 4; ++kt) {
                o0 = mfma16(vb[kt], pa[kt], o0);
                o1 = mfma16(vx[kt], pa[kt], o1);
            }
            const int t = shalf * 16 + lm;
            st4pk(&sO[swz128(t, fs  + quad * 4)],
                  o0[0] * inv, o0[1] * inv, o0[2] * inv, o0[3] * inv);
            st4pk(&sO[swz128(t, pfs + quad * 4)],
                  o1[0] * inv, o1[1] * inv, o1[2] * inv, o1[3] * inv);
        }

        // ---------- residual: bf16 -> bit-exact from LDS staging; fp32 -> global ----------
        float4 res[2];
        #pragma unroll
        for (int nt = 0; nt < 2; ++nt) {
            const int t = nt * 16 + lm;
            if (isBf16) {
                uint2 y = *(const uint2*)&sVehB[swz128(t, fs + quad * 4)];
                res[nt] = make_float4(bf1((unsigned short)(y.x & 0xFFFF)),
                                      bf1((unsigned short)(y.x >> 16)),
                                      bf1((unsigned short)(y.y & 0xFFFF)),
                                      bf1((unsigned short)(y.y >> 16)));
            } else {
                res[nt] = make_float4(0.f, 0.f, 0.f, 0.f);
                if (t < T_) {
                    const size_t off = ((size_t)t * (B_ * V_) + bv) * F_ + fs + quad * 4;
                    res[nt] = *(const float4*)((const float*)veh + off);
                }
            }
        }
        BAR_LDS();   // sO visible; stage loads STILL in flight

        // ---------- Phase E (swapped: A=Wc, JIT): out = O @ Wc^T + veh ----------
        {
            bf16x8 wc[4];
            #pragma unroll
            for (int kt = 0; kt < 4; ++kt)
                wc[kt] = ldWfrag(Wc, (fs + lm) * 128 + kt * 32 + quad * 8, isBf16);
            f32x4 acc[2];
            acc[0] = (f32x4)0.f; acc[1] = (f32x4)0.f;
            #pragma unroll
            for (int kt = 0; kt < 4; ++kt) {
                bf16x8 b[2];
                #pragma unroll
                for (int nt = 0; nt < 2; ++nt)
                    b[nt] = *(const bf16x8*)&sO[swz128(nt * 16 + lm, kt * 32 + quad * 8)];
                #pragma unroll
                for (int nt = 0; nt < 2; ++nt) acc[nt] = MFMA(wc[kt], b[nt], acc[nt]);    // C[g][t]
            }
            #pragma unroll
            for (int nt = 0; nt < 2; ++nt) {
                const int t = nt * 16 + lm;
                if (t < T_) {
                    const size_t off = ((size_t)t * (B_ * V_) + bv) * F_ + fs + quad * 4;
                    float4 o = make_float4(acc[nt][0] + res[nt].x, acc[nt][1] + res[nt].y,
                                           acc[nt][2] + res[nt].z, acc[nt][3] + res[nt].w);
                    *(float4*)&outp[off] = o;
                }
            }
        }
        // next iteration's BAR_VM separates all waves' phase E from the
        // overwrite of this bv's staging buffer.
    }
}

extern "C" void kernel_launch(void* const* d_in, const int* in_sizes, int n_in,
                              void* d_out, int out_size, void* d_ws, size_t ws_size,
                              hipStream_t stream) {
    (void)in_sizes; (void)n_in; (void)out_size; (void)d_ws; (void)ws_size;
    lane_attn_kernel<<<dim3(B_ * V_ / G_), dim3(512), 0, stream>>>(
        d_in[0], d_in[1], d_in[2], d_in[3], d_in[4], d_in[5], d_in[6],
        (float*)d_out);
}